// Round 10
// baseline (44804.239 us; speedup 1.0000x reference)
//
#include <hip/hip_runtime.h>
#include <hip/hip_fp16.h>
#include <math.h>

#define NBLK   32
#define BS     256
#define NSTATE 17
#define NH     256
#define NX     273      // NH + NSTATE
#define WID    1024
#define NT     64
#define NSUB   8
#define ROWS_H (WID/NBLK)   // 32 rows/block, 1024-wide layers
#define ROWS_L (NH/NBLK)    // 8 rows/block, 256-wide output layer

typedef unsigned long long u64;

__device__ __forceinline__ float softplus_f(float v) {
    return fmaxf(v, 0.f) + log1pf(expf(-fabsf(v)));
}

// ---- r3's proven fused tag+payload protocol (RELAXED AGENT), unchanged ----
__device__ __forceinline__ void st_tag(u64* p, float v, unsigned R) {
    u64 w = ((u64)R << 32) | (u64)__float_as_uint(v);
    __hip_atomic_store(p, w, __ATOMIC_RELAXED, __HIP_MEMORY_SCOPE_AGENT);
}
__device__ __forceinline__ u64 ld_tag(const u64* p) {
    return __hip_atomic_load(p, __ATOMIC_RELAXED, __HIP_MEMORY_SCOPE_AGENT);
}
__device__ __forceinline__ void poll_z(const u64* __restrict__ buf, unsigned R,
                                       float* __restrict__ z_s, int t) {
    float v[4];
    unsigned done = 0;
    while (done != 0xFu) {
        #pragma unroll
        for (int i = 0; i < 4; i++) {
            if (!(done & (1u << i))) {
                u64 w = ld_tag(buf + t + i * 256);
                if ((unsigned)(w >> 32) == R) {
                    v[i] = __uint_as_float((unsigned)w);
                    done |= 1u << i;
                }
            }
        }
    }
    #pragma unroll
    for (int i = 0; i < 4; i++) z_s[t + i * 256] = v[i];
    __syncthreads();
}

extern "C" __global__ __launch_bounds__(BS, 1) void ode_kernel(
    const float* __restrict__ ts,   const float* __restrict__ W0,
    const float* __restrict__ b0,   const float* __restrict__ Wh,
    const float* __restrict__ bh,   const float* __restrict__ Wl,
    const float* __restrict__ bl,   const float* __restrict__ betaW,
    const float* __restrict__ betab,const float* __restrict__ hvec,
    const float* __restrict__ scale,const float* __restrict__ y0log,
    float* __restrict__ out, u64* zA, u64* zB, u64* dhb)
{
    const int t   = threadIdx.x;
    const int blk = blockIdx.x;

    __shared__ __align__(16) float z_s[WID];
    __shared__ float w0_lds[ROWS_H * NX];      // 32x273 fp32 = 35 KB
    __shared__ __align__(16) float wl_lds[ROWS_L * WID];  // 8x1024 fp32 = 32 KB
    __shared__ float y_s[NX], yn_s[NX], x_s[NX], xm[NX], k_s[NX];
    __shared__ float red[4];
    __shared__ float dt_sh;

    const int lane16 = t & 15, rowq  = t >> 4;   // 16 rows in flight, 16 lanes/row
    const int lane64 = t & 63, rquad = t >> 6;   // 4 rows in flight, 64 lanes/row

    // ================= startup: make weights resident =================
    // Hidden layers: this block's 32 rows x 3 layers, packed fp16x2 in VGPRs.
    // Per thread: rows rowq & rowq+16, cols lane16*4 + i*64 (+0..3), i<16.
    // 3*2*32 = 192 VGPRs. fp16 RNE rel err ~6e-4; tolerance is 1.2e-2.
    __half2 whp[3][2][32];
    float bhr[3][2];
    #pragma unroll
    for (int l = 0; l < 3; l++) {
        #pragma unroll
        for (int c = 0; c < 2; c++) {
            const int r = blk * ROWS_H + rowq + 16 * c;
            const float* wr = Wh + (size_t)l * WID * WID + (size_t)r * WID;
            #pragma unroll
            for (int i = 0; i < 16; i++) {
                float4 w4 = *(const float4*)(wr + lane16 * 4 + i * 64);
                whp[l][c][2 * i]     = __halves2half2(__float2half(w4.x), __float2half(w4.y));
                whp[l][c][2 * i + 1] = __halves2half2(__float2half(w4.z), __float2half(w4.w));
            }
            bhr[l][c] = bh[l * WID + r];
        }
    }
    float b0r[2], blr[2];
    #pragma unroll
    for (int c = 0; c < 2; c++) {
        b0r[c] = b0[blk * ROWS_H + rowq + 16 * c];
        blr[c] = bl[blk * ROWS_L + rquad + 4 * c];
    }
    // L0 slice (fp32) into LDS
    for (int r = 0; r < ROWS_H; r++)
        for (int j = t; j < NX; j += BS)
            w0_lds[r * NX + j] = W0[(size_t)(blk * ROWS_H + r) * NX + j];
    // Wl slice (fp32) into LDS
    for (int r = 0; r < ROWS_L; r++)
        for (int j = t; j < WID; j += BS)
            wl_lds[r * WID + j] = Wl[(size_t)(blk * ROWS_L + r) * WID + j];

    const float scale0 = scale[0];
    const float betab0 = betab[0];
    unsigned R = 0;

    // ---- y0 = [softmax(y0_log), hvec] ----
    if (t < NSTATE) {
        float m = -1e30f;
        for (int j = 0; j < NSTATE; j++) m = fmaxf(m, y0log[j]);
        float ssum = 0.f;
        for (int j = 0; j < NSTATE; j++) ssum += expf(y0log[j] - m);
        y_s[t] = expf(y0log[t] - m) / ssum;
    }
    y_s[NSTATE + t] = hvec[t];
    __syncthreads();

    if (blk == 0) {
        if (t < NSTATE) out[t] = y_s[t];
        out[NT * NSTATE + t] = y_s[NSTATE + t];
    }

    const float c_xi = 13.f / 12.f, c_mu = 0.041f / 12.f, c_sig = 91.f / 12.f,
                c_nu = 36.f / 12.f, c_gam = 1.8f / 12.f;

    for (int iv = 0; iv < NT - 1; iv++) {
        if (t == 0) dt_sh = (ts[iv + 1] - ts[iv]) * (1.f / NSUB);
        __syncthreads();
        const float dt = dt_sh;

        for (int sub = 0; sub < NSUB; sub++) {
            for (int i = t; i < NX; i += BS) yn_s[i] = y_s[i];

            for (int s = 0; s < 4; s++) {
                const float a = (s == 0) ? 0.f : ((s == 3) ? 1.f : 0.5f);
                const float w = ((s == 0) || (s == 3)) ? dt * (1.f / 6.f) : dt * (1.f / 3.f);

                // ---- stage input x = y + a*dt*k_prev ----
                if (s == 0) { for (int i = t; i < NX; i += BS) x_s[i] = y_s[i]; }
                else        { for (int i = t; i < NX; i += BS) x_s[i] = y_s[i] + a * dt * k_s[i]; }
                __syncthreads();

                // ---- MLP input reorder + beta head partial ----
                xm[t] = x_s[NSTATE + t];
                if (t < NSTATE) xm[NH + t] = x_s[t];
                float p = betaW[t] * x_s[NSTATE + t];
                #pragma unroll
                for (int m = 1; m < 64; m <<= 1) p += __shfl_xor(p, m, 64);
                if ((t & 63) == 0) red[t >> 6] = p;
                __syncthreads();

                // ---- dstate (redundant per block, thread 0) ----
                if (t == 0) {
                    float sd  = red[0] + red[1] + red[2] + red[3] + betab0;
                    float bb1 = 8.f / (1.f + expf(-sd)) + 25.f;
                    float bb2 = 0.5f * bb1, bb3 = 0.35f * bb1, bb4 = 0.25f * bb1;
                    float M  = x_s[0],  S1 = x_s[1],  E1 = x_s[2],  E2 = x_s[3];
                    float E3 = x_s[4],  E4 = x_s[5],  I1 = x_s[6],  I2 = x_s[7];
                    float I3 = x_s[8],  I4 = x_s[9],  R1 = x_s[10], R2 = x_s[11];
                    float R3 = x_s[12], R4 = x_s[13], S2 = x_s[14], S3 = x_s[15];
                    float S4 = x_s[16];
                    float I = I1 + I2 + I3 + I4, Rs = R1 + R2 + R3 + R4;
                    k_s[0]  = Rs * c_mu - (c_xi + c_mu) * M;
                    k_s[1]  = c_mu * (1.f - Rs) + c_xi * M - c_mu * S1 - bb1 * I * S1;
                    k_s[2]  = bb1 * I * S1 - (c_mu + c_sig) * E1;
                    k_s[3]  = bb2 * I * S2 - (c_mu + c_sig) * E2;
                    k_s[4]  = bb3 * I * S3 - (c_mu + c_sig) * E3;
                    k_s[5]  = bb4 * I * S4 - (c_mu + c_sig) * E4;
                    k_s[6]  = c_sig * E1 - (c_nu + c_mu) * I1;
                    k_s[7]  = c_sig * E2 - (c_nu + c_mu) * I2;
                    k_s[8]  = c_sig * E3 - (c_nu + c_mu) * I3;
                    k_s[9]  = c_sig * E4 - (c_nu + c_mu) * I4;
                    k_s[10] = c_nu * I1 - (c_mu + c_gam) * R1;
                    k_s[11] = c_nu * I2 - (c_mu + c_gam) * R2;
                    k_s[12] = c_nu * I3 - (c_mu + c_gam) * R3;
                    k_s[13] = c_nu * I4 - (c_mu + c_gam) * R4;
                    k_s[14] = c_gam * R1 - c_mu * S2 - bb2 * I * S2;
                    k_s[15] = c_gam * R2 - c_mu * S3 - bb3 * I * S3;
                    k_s[16] = c_gam * (R3 + R4) - c_mu * S4 - bb4 * I * S4;
                }
                __syncthreads();

                // ---- L0: 32 rows/block from LDS weights (input xm local) ----
                ++R;
                #pragma unroll
                for (int c = 0; c < 2; c++) {
                    const int row = rowq + 16 * c;
                    const float* wr = w0_lds + row * NX;
                    float acc = 0.f;
                    #pragma unroll
                    for (int i = 0; i < 17; i++) {
                        const int col = lane16 + 16 * i;   // <= 271
                        acc += wr[col] * xm[col];
                    }
                    if (lane16 == 0) acc += wr[272] * xm[272];
                    #pragma unroll
                    for (int m = 1; m < 16; m <<= 1) acc += __shfl_xor(acc, m, 16);
                    if (lane16 == 0)
                        st_tag(&zA[blk * ROWS_H + row], softplus_f(acc + b0r[c]), R);
                }

                // ---- hidden layers 1..3: weights in VGPRs (fp16x2) ----
                #pragma unroll
                for (int l = 0; l < 3; l++) {
                    const u64* zin = (l == 1) ? zB : zA;
                    u64*      zout = (l == 1) ? zA : zB;

                    poll_z(zin, R, z_s, t);
                    ++R;

                    #pragma unroll
                    for (int c = 0; c < 2; c++) {
                        float acc = 0.f;
                        #pragma unroll
                        for (int i = 0; i < 16; i++) {
                            float4 zv = *(const float4*)(z_s + lane16 * 4 + i * 64);
                            float2 fa = __half22float2(whp[l][c][2 * i]);
                            float2 fb = __half22float2(whp[l][c][2 * i + 1]);
                            acc += fa.x * zv.x + fa.y * zv.y + fb.x * zv.z + fb.y * zv.w;
                        }
                        #pragma unroll
                        for (int m = 1; m < 16; m <<= 1) acc += __shfl_xor(acc, m, 16);
                        if (lane16 == 0)
                            st_tag(&zout[blk * ROWS_H + rowq + 16 * c],
                                   softplus_f(acc + bhr[l][c]), R);
                    }
                }

                // ---- Wl: 8 rows/block from LDS weights; tanh epilogue ----
                poll_z(zB, R, z_s, t);   // h3 lives in zB
                ++R;
                #pragma unroll
                for (int c = 0; c < 2; c++) {
                    const int row = rquad + 4 * c;
                    float acc = 0.f;
                    #pragma unroll
                    for (int i = 0; i < 4; i++) {
                        float4 wv = *(const float4*)(wl_lds + row * WID + lane64 * 4 + i * 256);
                        float4 zv = *(const float4*)(z_s + lane64 * 4 + i * 256);
                        acc += wv.x * zv.x + wv.y * zv.y + wv.z * zv.z + wv.w * zv.w;
                    }
                    #pragma unroll
                    for (int m = 1; m < 64; m <<= 1) acc += __shfl_xor(acc, m, 64);
                    if (lane64 == 0)
                        st_tag(&dhb[blk * ROWS_L + row],
                               scale0 * tanhf(0.01f * (acc + blr[c])), R);
                }

                // ---- gather dh (tagged poll, one word per thread) ----
                {
                    u64 wv;
                    do { wv = ld_tag(dhb + t); } while ((unsigned)(wv >> 32) != R);
                    k_s[NSTATE + t] = __uint_as_float((unsigned)wv);
                }
                __syncthreads();
                for (int i = t; i < NX; i += BS) yn_s[i] += w * k_s[i];
            } // stages

            __syncthreads();
            for (int i = t; i < NX; i += BS) y_s[i] = yn_s[i];
            __syncthreads();
        } // substeps

        if (blk == 0) {
            if (t < NSTATE) out[(iv + 1) * NSTATE + t] = y_s[t];
            out[NT * NSTATE + (iv + 1) * NH + t] = y_s[NSTATE + t];
        }
    } // intervals
}

extern "C" void kernel_launch(void* const* d_in, const int* in_sizes, int n_in,
                              void* d_out, int out_size, void* d_ws, size_t ws_size,
                              hipStream_t stream) {
    const float* ts    = (const float*)d_in[0];
    const float* W0    = (const float*)d_in[1];
    const float* b0    = (const float*)d_in[2];
    const float* Wh    = (const float*)d_in[3];
    const float* bh    = (const float*)d_in[4];
    const float* Wl    = (const float*)d_in[5];
    const float* bl    = (const float*)d_in[6];
    const float* betaW = (const float*)d_in[7];
    const float* betab = (const float*)d_in[8];
    const float* hvec  = (const float*)d_in[9];
    const float* scale = (const float*)d_in[10];
    const float* y0log = (const float*)d_in[11];
    float* out = (float*)d_out;

    u64* zA  = (u64*)d_ws;                          // 1024*8 = 8 KB
    u64* zB  = (u64*)((char*)d_ws + 8192);          // 8 KB
    u64* dhb = (u64*)((char*)d_ws + 16384);         // 2 KB

    // zero all tags (tag 0 != any R>=1; harness poison 0xAA... also != any R)
    hipMemsetAsync(d_ws, 0, 18432, stream);
    hipLaunchKernelGGL(ode_kernel, dim3(NBLK), dim3(BS), 0, stream,
                       ts, W0, b0, Wh, bh, Wl, bl, betaW, betab, hvec, scale,
                       y0log, out, zA, zB, dhb);
}